// Round 1
// baseline (6244.720 us; speedup 1.0000x reference)
//
#include <hip/hip_runtime.h>

#define T_LEN 2048
#define BSZ   2
#define EMB   1280
#define NH    20
#define HD    64
#define NBH   (BSZ*NH)      // 40
#define NR    (T_LEN*BSZ)   // 4096
#define SCALE 0.125f        // HEAD_DIM ** -0.5

#define NEG_INF (-__builtin_inff())

// ---------------- K1: QKV projection GEMM ----------------
// C[4096,1280] = X @ W + b  (scaled for Q), written head-major [b*NH+h][t][d]
__global__ __launch_bounds__(256) void k_gemm_qkv(
    const float* __restrict__ X,
    const float* __restrict__ Wq, const float* __restrict__ bq,
    const float* __restrict__ Wk, const float* __restrict__ bk,
    const float* __restrict__ Wv, const float* __restrict__ bv,
    float* __restrict__ Q, float* __restrict__ K, float* __restrict__ V)
{
    const int which = blockIdx.z;
    const float* __restrict__ W    = (which==0) ? Wq : (which==1) ? Wk : Wv;
    const float* __restrict__ bias = (which==0) ? bq : (which==1) ? bk : bv;
    float* __restrict__ dst        = (which==0) ? Q  : (which==1) ? K  : V;
    const float scale = (which==0) ? SCALE : 1.0f;

    const int bm = blockIdx.y * 64;
    const int bn = blockIdx.x * 64;
    const int t  = threadIdx.x;
    const int tx = t & 15, ty = t >> 4;

    __shared__ float Xs[16][68];   // [k][m]
    __shared__ float Ws[16][68];   // [k][n]

    float acc[4][4] = {};

    for (int kt = 0; kt < EMB; kt += 16) {
        {
            int lin = t * 4;
            int row = lin >> 4, col = lin & 15;
            float4 xv = *(const float4*)(X + (size_t)(bm+row)*EMB + kt + col);
            Xs[col+0][row] = xv.x; Xs[col+1][row] = xv.y;
            Xs[col+2][row] = xv.z; Xs[col+3][row] = xv.w;
        }
        {
            int lin = t * 4;
            int row = lin >> 6, col = lin & 63;
            *(float4*)&Ws[row][col] = *(const float4*)(W + (size_t)(kt+row)*EMB + bn + col);
        }
        __syncthreads();
        #pragma unroll
        for (int k = 0; k < 16; ++k) {
            float4 a = *(const float4*)&Xs[k][ty*4];
            float4 b = *(const float4*)&Ws[k][tx*4];
            const float av[4]  = {a.x,a.y,a.z,a.w};
            const float bv4[4] = {b.x,b.y,b.z,b.w};
            #pragma unroll
            for (int i=0;i<4;++i)
                #pragma unroll
                for (int j=0;j<4;++j)
                    acc[i][j] = fmaf(av[i], bv4[j], acc[i][j]);
        }
        __syncthreads();
    }
    #pragma unroll
    for (int i=0;i<4;++i) {
        int r = bm + ty*4 + i;
        int tt = r >> 1, bb = r & 1;   // r = t*BSZ + b
        #pragma unroll
        for (int j=0;j<4;++j) {
            int c = bn + tx*4 + j;
            int h = c >> 6, d = c & 63;
            dst[(((size_t)(bb*NH+h))*T_LEN + tt)*HD + d] = (acc[i][j] + bias[c]) * scale;
        }
    }
}

// ---------------- K2: per-row softmax stats (m, 1/l) ----------------
__global__ __launch_bounds__(256) void k_stats(
    const float* __restrict__ Q, const float* __restrict__ K,
    const int* __restrict__ kpm,
    float* __restrict__ Mrow, float* __restrict__ Linv)
{
    const int qt = blockIdx.x;   // 64 q-tiles of 32
    const int bh = blockIdx.y;   // 40
    const int b  = bh / NH;
    const int t  = threadIdx.x;
    const int ty = t >> 3, tx = t & 7;

    __shared__ float Qs[32][68];
    __shared__ float Ks[32][68];
    __shared__ int   msk[32];
    __shared__ float Mp[32][8], Lp[32][8];

    {
        int lin = t * 8;
        int row = lin >> 6, col = lin & 63;
        const float* src = Q + ((size_t)bh*T_LEN + qt*32 + row)*HD + col;
        *(float4*)&Qs[row][col]   = *(const float4*)src;
        *(float4*)&Qs[row][col+4] = *(const float4*)(src+4);
    }

    float m = NEG_INF, l = 0.f;

    for (int kt = 0; kt < T_LEN; kt += 32) {
        __syncthreads();
        {
            int lin = t * 8;
            int row = lin >> 6, col = lin & 63;
            const float* src = K + ((size_t)bh*T_LEN + kt + row)*HD + col;
            *(float4*)&Ks[row][col]   = *(const float4*)src;
            *(float4*)&Ks[row][col+4] = *(const float4*)(src+4);
        }
        if (t < 32) msk[t] = kpm[b*T_LEN + kt + t];
        __syncthreads();

        float s[4] = {0.f,0.f,0.f,0.f};
        #pragma unroll
        for (int d = 0; d < HD; d += 4) {
            float4 qv = *(const float4*)&Qs[ty][d];
            #pragma unroll
            for (int c = 0; c < 4; ++c) {
                float4 kv = *(const float4*)&Ks[tx + 8*c][d];
                s[c] += qv.x*kv.x + qv.y*kv.y + qv.z*kv.z + qv.w*kv.w;
            }
        }
        #pragma unroll
        for (int c = 0; c < 4; ++c) {
            if (!msk[tx + 8*c]) {
                float sv = s[c];
                float mn = fmaxf(m, sv);
                l = l * __expf(m - mn) + __expf(sv - mn);
                m = mn;
            }
        }
    }
    Mp[ty][tx] = m; Lp[ty][tx] = l;
    __syncthreads();
    if (t < 32) {
        float M = NEG_INF;
        #pragma unroll
        for (int i=0;i<8;++i) M = fmaxf(M, Mp[t][i]);
        float L = 0.f;
        #pragma unroll
        for (int i=0;i<8;++i) L += Lp[t][i] * __expf(Mp[t][i] - M);
        Mrow[(size_t)bh*T_LEN + qt*32 + t] = M;
        Linv[(size_t)bh*T_LEN + qt*32 + t] = 1.0f / L;
    }
}

// ---------------- K3: P = softmax(S), O = P @ V ----------------
__global__ __launch_bounds__(256) void k_pv(
    const float* __restrict__ Q, const float* __restrict__ K, const float* __restrict__ V,
    const int* __restrict__ kpm,
    const float* __restrict__ Mrow, const float* __restrict__ Linv,
    float* __restrict__ AttnMid)   // [4096][1280], r = t*BSZ + b
{
    const int qt = blockIdx.x;
    const int bh = blockIdx.y;
    const int b  = bh / NH, h = bh % NH;
    const int t  = threadIdx.x;
    const int ty = t >> 3, tx = t & 7;

    __shared__ float Qs[32][68];
    __shared__ float Ks[32][68];
    __shared__ float Vs[32][68];
    __shared__ float Ps[32][36];
    __shared__ float Msh[32], Lish[32];
    __shared__ int   msk[32];

    {
        int lin = t * 8;
        int row = lin >> 6, col = lin & 63;
        const float* src = Q + ((size_t)bh*T_LEN + qt*32 + row)*HD + col;
        *(float4*)&Qs[row][col]   = *(const float4*)src;
        *(float4*)&Qs[row][col+4] = *(const float4*)(src+4);
    }
    if (t < 32) {
        Msh[t]  = Mrow[(size_t)bh*T_LEN + qt*32 + t];
        Lish[t] = Linv[(size_t)bh*T_LEN + qt*32 + t];
    }

    float o[8] = {};

    for (int kt = 0; kt < T_LEN; kt += 32) {
        __syncthreads();
        {
            int lin = t * 8;
            int row = lin >> 6, col = lin & 63;
            const float* srcK = K + ((size_t)bh*T_LEN + kt + row)*HD + col;
            *(float4*)&Ks[row][col]   = *(const float4*)srcK;
            *(float4*)&Ks[row][col+4] = *(const float4*)(srcK+4);
            const float* srcV = V + ((size_t)bh*T_LEN + kt + row)*HD + col;
            *(float4*)&Vs[row][col]   = *(const float4*)srcV;
            *(float4*)&Vs[row][col+4] = *(const float4*)(srcV+4);
        }
        if (t < 32) msk[t] = kpm[b*T_LEN + kt + t];
        __syncthreads();

        float s[4] = {0.f,0.f,0.f,0.f};
        #pragma unroll
        for (int d = 0; d < HD; d += 4) {
            float4 qv = *(const float4*)&Qs[ty][d];
            #pragma unroll
            for (int c = 0; c < 4; ++c) {
                float4 kv = *(const float4*)&Ks[tx + 8*c][d];
                s[c] += qv.x*kv.x + qv.y*kv.y + qv.z*kv.z + qv.w*kv.w;
            }
        }
        #pragma unroll
        for (int c = 0; c < 4; ++c) {
            float p = msk[tx + 8*c] ? 0.f : __expf(s[c] - Msh[ty]) * Lish[ty];
            Ps[ty][tx + 8*c] = p;
        }
        __syncthreads();
        #pragma unroll
        for (int k = 0; k < 32; ++k) {
            float pk = Ps[ty][k];
            float4 v1 = *(const float4*)&Vs[k][tx*8];
            float4 v2 = *(const float4*)&Vs[k][tx*8+4];
            o[0] = fmaf(pk, v1.x, o[0]); o[1] = fmaf(pk, v1.y, o[1]);
            o[2] = fmaf(pk, v1.z, o[2]); o[3] = fmaf(pk, v1.w, o[3]);
            o[4] = fmaf(pk, v2.x, o[4]); o[5] = fmaf(pk, v2.y, o[5]);
            o[6] = fmaf(pk, v2.z, o[6]); o[7] = fmaf(pk, v2.w, o[7]);
        }
    }
    int qrow = qt*32 + ty;
    int r = qrow * BSZ + b;
    float4 w1 = make_float4(o[0],o[1],o[2],o[3]);
    float4 w2 = make_float4(o[4],o[5],o[6],o[7]);
    *(float4*)(AttnMid + (size_t)r*EMB + h*HD + tx*8)     = w1;
    *(float4*)(AttnMid + (size_t)r*EMB + h*HD + tx*8 + 4) = w2;
}

// ---------------- K4: avg_weights = mean over heads of P ----------------
__global__ __launch_bounds__(256) void k_meanw(
    const float* __restrict__ Q, const float* __restrict__ K,
    const int* __restrict__ kpm,
    const float* __restrict__ Mrow, const float* __restrict__ Linv,
    float* __restrict__ avg)   // [BSZ][T_LEN][T_LEN]
{
    const int kt = blockIdx.x;   // 32 k-tiles of 64
    const int qt = blockIdx.y;   // 64 q-tiles of 32
    const int b  = blockIdx.z;
    const int t  = threadIdx.x;
    const int ty = t >> 3, tx = t & 7;

    __shared__ float Qs[32][68];
    __shared__ float Ks[64][68];
    __shared__ float Msh[32], Lish[32];
    __shared__ int   msk[64];

    if (t < 64) msk[t] = kpm[b*T_LEN + kt*64 + t];

    float acc[8] = {};

    for (int h = 0; h < NH; ++h) {
        const int bh = b*NH + h;
        __syncthreads();
        {
            int lin = t * 8;
            int row = lin >> 6, col = lin & 63;
            const float* src = Q + ((size_t)bh*T_LEN + qt*32 + row)*HD + col;
            *(float4*)&Qs[row][col]   = *(const float4*)src;
            *(float4*)&Qs[row][col+4] = *(const float4*)(src+4);
        }
        {
            int row = t >> 2, col = (t & 3) * 16;
            const float* src = K + ((size_t)bh*T_LEN + kt*64 + row)*HD + col;
            #pragma unroll
            for (int j = 0; j < 4; ++j)
                *(float4*)&Ks[row][col + 4*j] = *(const float4*)(src + 4*j);
        }
        if (t < 32) {
            Msh[t]  = Mrow[(size_t)bh*T_LEN + qt*32 + t];
            Lish[t] = Linv[(size_t)bh*T_LEN + qt*32 + t];
        }
        __syncthreads();

        float s[8] = {};
        #pragma unroll
        for (int d = 0; d < HD; d += 4) {
            float4 qv = *(const float4*)&Qs[ty][d];
            #pragma unroll
            for (int j = 0; j < 8; ++j) {
                float4 kv = *(const float4*)&Ks[tx + 8*j][d];
                s[j] += qv.x*kv.x + qv.y*kv.y + qv.z*kv.z + qv.w*kv.w;
            }
        }
        float mv = Msh[ty], li = Lish[ty] * (1.0f/NH);
        #pragma unroll
        for (int j = 0; j < 8; ++j) {
            if (!msk[tx + 8*j])
                acc[j] += __expf(s[j] - mv) * li;
        }
    }
    int q = qt*32 + ty;
    size_t base = ((size_t)b*T_LEN + q) * T_LEN + (size_t)kt*64;
    #pragma unroll
    for (int j = 0; j < 8; ++j)
        avg[base + tx + 8*j] = acc[j];
}

// ---------------- K5: output projection ----------------
__global__ __launch_bounds__(256) void k_gemm_out(
    const float* __restrict__ X, const float* __restrict__ Wo,
    const float* __restrict__ bo, float* __restrict__ out)
{
    const int bm = blockIdx.y * 64;
    const int bn = blockIdx.x * 64;
    const int t  = threadIdx.x;
    const int tx = t & 15, ty = t >> 4;

    __shared__ float Xs[16][68];
    __shared__ float Ws[16][68];

    float acc[4][4] = {};
    for (int kt = 0; kt < EMB; kt += 16) {
        {
            int lin = t * 4;
            int row = lin >> 4, col = lin & 15;
            float4 xv = *(const float4*)(X + (size_t)(bm+row)*EMB + kt + col);
            Xs[col+0][row] = xv.x; Xs[col+1][row] = xv.y;
            Xs[col+2][row] = xv.z; Xs[col+3][row] = xv.w;
        }
        {
            int lin = t * 4;
            int row = lin >> 6, col = lin & 63;
            *(float4*)&Ws[row][col] = *(const float4*)(Wo + (size_t)(kt+row)*EMB + bn + col);
        }
        __syncthreads();
        #pragma unroll
        for (int k = 0; k < 16; ++k) {
            float4 a = *(const float4*)&Xs[k][ty*4];
            float4 b = *(const float4*)&Ws[k][tx*4];
            const float av[4]  = {a.x,a.y,a.z,a.w};
            const float bv4[4] = {b.x,b.y,b.z,b.w};
            #pragma unroll
            for (int i=0;i<4;++i)
                #pragma unroll
                for (int j=0;j<4;++j)
                    acc[i][j] = fmaf(av[i], bv4[j], acc[i][j]);
        }
        __syncthreads();
    }
    #pragma unroll
    for (int i=0;i<4;++i) {
        int r = bm + ty*4 + i;
        int c = bn + tx*4;
        float4 w = make_float4(acc[i][0]+bo[c], acc[i][1]+bo[c+1],
                               acc[i][2]+bo[c+2], acc[i][3]+bo[c+3]);
        *(float4*)(out + (size_t)r*EMB + c) = w;
    }
}

extern "C" void kernel_launch(void* const* d_in, const int* in_sizes, int n_in,
                              void* d_out, int out_size, void* d_ws, size_t ws_size,
                              hipStream_t stream) {
    const float* X   = (const float*)d_in[0];
    const int*   kpm = (const int*)  d_in[1];
    const float* Wq  = (const float*)d_in[2];
    const float* bq  = (const float*)d_in[3];
    const float* Wk  = (const float*)d_in[4];
    const float* bk  = (const float*)d_in[5];
    const float* Wv  = (const float*)d_in[6];
    const float* bv  = (const float*)d_in[7];
    const float* Wo  = (const float*)d_in[8];
    const float* bo  = (const float*)d_in[9];

    float* out = (float*)d_out;
    float* ws  = (float*)d_ws;

    const size_t QKV = (size_t)NBH * T_LEN * HD;   // 5,242,880
    float* Q       = ws;
    float* K       = Q + QKV;
    float* V       = K + QKV;
    float* Mrow    = V + QKV;
    float* Linv    = Mrow + (size_t)NBH * T_LEN;
    float* AttnMid = Linv + (size_t)NBH * T_LEN;

    float* attn_out = out;                 // [T_LEN, BSZ, EMB]
    float* avg      = out + (size_t)T_LEN * BSZ * EMB;  // [BSZ, T_LEN, T_LEN]

    k_gemm_qkv<<<dim3(EMB/64, NR/64, 3), 256, 0, stream>>>(X, Wq,bq, Wk,bk, Wv,bv, Q, K, V);
    k_stats   <<<dim3(T_LEN/32, NBH),    256, 0, stream>>>(Q, K, kpm, Mrow, Linv);
    k_pv      <<<dim3(T_LEN/32, NBH),    256, 0, stream>>>(Q, K, V, kpm, Mrow, Linv, AttnMid);
    k_meanw   <<<dim3(T_LEN/64, T_LEN/32, BSZ), 256, 0, stream>>>(Q, K, kpm, Mrow, Linv, avg);
    k_gemm_out<<<dim3(EMB/64, NR/64),    256, 0, stream>>>(AttnMid, Wo, bo, attn_out);
}

// Round 2
// 2200.872 us; speedup vs baseline: 2.8374x; 2.8374x over previous
//
#include <hip/hip_runtime.h>

#define T_LEN 2048
#define BSZ   2
#define EMB   1280
#define NH    20
#define HD    64
#define NBH   (BSZ*NH)      // 40
#define NR    (T_LEN*BSZ)   // 4096
#define SCALE 0.125f        // HEAD_DIM ** -0.5

#define NEG_INF (-__builtin_inff())

// ---------------- K1: QKV projection GEMM ----------------
// C[4096,1280] = X @ W + b  (scaled for Q), written head-major [b*NH+h][t][d]
__global__ __launch_bounds__(256) void k_gemm_qkv(
    const float* __restrict__ X,
    const float* __restrict__ Wq, const float* __restrict__ bq,
    const float* __restrict__ Wk, const float* __restrict__ bk,
    const float* __restrict__ Wv, const float* __restrict__ bv,
    float* __restrict__ Q, float* __restrict__ K, float* __restrict__ V)
{
    const int which = blockIdx.z;
    const float* __restrict__ W    = (which==0) ? Wq : (which==1) ? Wk : Wv;
    const float* __restrict__ bias = (which==0) ? bq : (which==1) ? bk : bv;
    float* __restrict__ dst        = (which==0) ? Q  : (which==1) ? K  : V;
    const float scale = (which==0) ? SCALE : 1.0f;

    const int bm = blockIdx.y * 64;
    const int bn = blockIdx.x * 64;
    const int t  = threadIdx.x;
    const int tx = t & 15, ty = t >> 4;

    __shared__ float Xs[16][68];   // [k][m]
    __shared__ float Ws[16][68];   // [k][n]

    float acc[4][4] = {};

    for (int kt = 0; kt < EMB; kt += 16) {
        {
            int lin = t * 4;
            int row = lin >> 4, col = lin & 15;
            float4 xv = *(const float4*)(X + (size_t)(bm+row)*EMB + kt + col);
            Xs[col+0][row] = xv.x; Xs[col+1][row] = xv.y;
            Xs[col+2][row] = xv.z; Xs[col+3][row] = xv.w;
        }
        {
            int lin = t * 4;
            int row = lin >> 6, col = lin & 63;
            *(float4*)&Ws[row][col] = *(const float4*)(W + (size_t)(kt+row)*EMB + bn + col);
        }
        __syncthreads();
        #pragma unroll
        for (int k = 0; k < 16; ++k) {
            float4 a = *(const float4*)&Xs[k][ty*4];
            float4 b = *(const float4*)&Ws[k][tx*4];
            const float av[4]  = {a.x,a.y,a.z,a.w};
            const float bv4[4] = {b.x,b.y,b.z,b.w};
            #pragma unroll
            for (int i=0;i<4;++i)
                #pragma unroll
                for (int j=0;j<4;++j)
                    acc[i][j] = fmaf(av[i], bv4[j], acc[i][j]);
        }
        __syncthreads();
    }
    #pragma unroll
    for (int i=0;i<4;++i) {
        int r = bm + ty*4 + i;
        int tt = r >> 1, bb = r & 1;   // r = t*BSZ + b
        #pragma unroll
        for (int j=0;j<4;++j) {
            int c = bn + tx*4 + j;
            int h = c >> 6, d = c & 63;
            dst[(((size_t)(bb*NH+h))*T_LEN + tt)*HD + d] = (acc[i][j] + bias[c]) * scale;
        }
    }
}

// ---------------- K2: flash pv with online softmax; also emits Mrow/Linv ----
__global__ __launch_bounds__(256) void k_pv(
    const float* __restrict__ Q, const float* __restrict__ K, const float* __restrict__ V,
    const int* __restrict__ kpm,
    float* __restrict__ Mrow, float* __restrict__ Linv,
    float* __restrict__ AttnMid)   // [4096][1280], r = t*BSZ + b
{
    const int qt = blockIdx.x;
    const int bh = blockIdx.y;
    const int b  = bh / NH, h = bh % NH;
    const int t  = threadIdx.x;
    const int ty = t >> 3, tx = t & 7;

    __shared__ float Qs[32][68];
    __shared__ float Ks[32][68];
    __shared__ float Vs[32][68];
    __shared__ float Ps[32][36];
    __shared__ int   msk[32];

    {
        int lin = t * 8;
        int row = lin >> 6, col = lin & 63;
        const float* src = Q + ((size_t)bh*T_LEN + qt*32 + row)*HD + col;
        *(float4*)&Qs[row][col]   = *(const float4*)src;
        *(float4*)&Qs[row][col+4] = *(const float4*)(src+4);
    }

    float o[8] = {};
    float m = NEG_INF, l = 0.f;

    for (int kt = 0; kt < T_LEN; kt += 32) {
        __syncthreads();
        {
            int lin = t * 8;
            int row = lin >> 6, col = lin & 63;
            const float* srcK = K + ((size_t)bh*T_LEN + kt + row)*HD + col;
            *(float4*)&Ks[row][col]   = *(const float4*)srcK;
            *(float4*)&Ks[row][col+4] = *(const float4*)(srcK+4);
            const float* srcV = V + ((size_t)bh*T_LEN + kt + row)*HD + col;
            *(float4*)&Vs[row][col]   = *(const float4*)srcV;
            *(float4*)&Vs[row][col+4] = *(const float4*)(srcV+4);
        }
        if (t < 32) msk[t] = kpm[b*T_LEN + kt + t];
        __syncthreads();

        float s[4] = {0.f,0.f,0.f,0.f};
        #pragma unroll
        for (int d = 0; d < HD; d += 4) {
            float4 qv = *(const float4*)&Qs[ty][d];
            #pragma unroll
            for (int c = 0; c < 4; ++c) {
                float4 kv = *(const float4*)&Ks[tx + 8*c][d];
                s[c] += qv.x*kv.x + qv.y*kv.y + qv.z*kv.z + qv.w*kv.w;
            }
        }
        #pragma unroll
        for (int c = 0; c < 4; ++c)
            if (msk[tx + 8*c]) s[c] = NEG_INF;

        // online softmax bookkeeping (8 lanes per q-row, consecutive)
        float tmax = fmaxf(fmaxf(s[0], s[1]), fmaxf(s[2], s[3]));
        tmax = fmaxf(tmax, __shfl_xor(tmax, 1, 8));
        tmax = fmaxf(tmax, __shfl_xor(tmax, 2, 8));
        tmax = fmaxf(tmax, __shfl_xor(tmax, 4, 8));
        float m_new = fmaxf(m, tmax);

        float alpha, p[4];
        if (m_new == NEG_INF) {
            alpha = 1.f;
            p[0]=p[1]=p[2]=p[3]=0.f;
        } else {
            alpha = __expf(m - m_new);   // m==-inf -> 0
            #pragma unroll
            for (int c = 0; c < 4; ++c)
                p[c] = (s[c] == NEG_INF) ? 0.f : __expf(s[c] - m_new);
        }
        float psum = p[0]+p[1]+p[2]+p[3];
        psum += __shfl_xor(psum, 1, 8);
        psum += __shfl_xor(psum, 2, 8);
        psum += __shfl_xor(psum, 4, 8);
        l = l * alpha + psum;
        m = m_new;

        #pragma unroll
        for (int c = 0; c < 4; ++c)
            Ps[ty][tx + 8*c] = p[c];
        #pragma unroll
        for (int j = 0; j < 8; ++j) o[j] *= alpha;
        __syncthreads();

        #pragma unroll
        for (int k = 0; k < 32; ++k) {
            float pk = Ps[ty][k];
            float4 v1 = *(const float4*)&Vs[k][tx*8];
            float4 v2 = *(const float4*)&Vs[k][tx*8+4];
            o[0] = fmaf(pk, v1.x, o[0]); o[1] = fmaf(pk, v1.y, o[1]);
            o[2] = fmaf(pk, v1.z, o[2]); o[3] = fmaf(pk, v1.w, o[3]);
            o[4] = fmaf(pk, v2.x, o[4]); o[5] = fmaf(pk, v2.y, o[5]);
            o[6] = fmaf(pk, v2.z, o[6]); o[7] = fmaf(pk, v2.w, o[7]);
        }
    }

    float linv = 1.0f / l;
    #pragma unroll
    for (int j = 0; j < 8; ++j) o[j] *= linv;

    int qrow = qt*32 + ty;
    if (tx == 0) {
        Mrow[(size_t)bh*T_LEN + qrow] = m;
        Linv[(size_t)bh*T_LEN + qrow] = linv;
    }
    int r = qrow * BSZ + b;
    float4 w1 = make_float4(o[0],o[1],o[2],o[3]);
    float4 w2 = make_float4(o[4],o[5],o[6],o[7]);
    *(float4*)(AttnMid + (size_t)r*EMB + h*HD + tx*8)     = w1;
    *(float4*)(AttnMid + (size_t)r*EMB + h*HD + tx*8 + 4) = w2;
}

// ---------------- K3: avg_weights = mean over heads of P ----------------
// 128q x 64k tile per block; thread tile 4q x 8k; q-rows scattered (tq+32i),
// k-cols scattered (tk+8j) so all LDS b128 reads are conflict-free.
__global__ __launch_bounds__(256) void k_meanw(
    const float* __restrict__ Q, const float* __restrict__ K,
    const int* __restrict__ kpm,
    const float* __restrict__ Mrow, const float* __restrict__ Linv,
    float* __restrict__ avg)   // [BSZ][T_LEN][T_LEN]
{
    const int kt = blockIdx.x;   // 32 k-tiles of 64
    const int qt = blockIdx.y;   // 16 q-tiles of 128
    const int b  = blockIdx.z;
    const int t  = threadIdx.x;
    const int tq = t >> 3;       // 0..31
    const int tk = t & 7;        // 0..7

    __shared__ float Qs[128][68];
    __shared__ float Ks[64][68];
    __shared__ float Msh[128], Lish[128];
    __shared__ int   msk[64];

    if (t < 64) msk[t] = kpm[b*T_LEN + kt*64 + t];

    float acc[4][8] = {};

    for (int h = 0; h < NH; ++h) {
        const int bh = b*NH + h;
        __syncthreads();
        {   // stage Q tile: 128x64 floats, coalesced float4
            const float* src = Q + ((size_t)bh*T_LEN + qt*128)*HD;
            #pragma unroll
            for (int p = 0; p < 8; ++p) {
                int idx = p*256 + t;          // float4 index, 16 per row
                int q = idx >> 4, d = (idx & 15) * 4;
                *(float4*)&Qs[q][d] = *(const float4*)(src + q*HD + d);
            }
        }
        {   // stage K tile: 64x64 floats
            const float* srcK = K + ((size_t)bh*T_LEN + kt*64)*HD;
            #pragma unroll
            for (int p = 0; p < 4; ++p) {
                int idx = p*256 + t;
                int r = idx >> 4, d = (idx & 15) * 4;
                *(float4*)&Ks[r][d] = *(const float4*)(srcK + r*HD + d);
            }
        }
        if (t < 128) {
            Msh[t]  = Mrow[(size_t)bh*T_LEN + qt*128 + t];
            Lish[t] = Linv[(size_t)bh*T_LEN + qt*128 + t];
        }
        __syncthreads();

        float s[4][8] = {};
        #pragma unroll 1
        for (int d = 0; d < HD; d += 4) {
            float4 qv[4];
            #pragma unroll
            for (int i=0;i<4;++i) qv[i] = *(const float4*)&Qs[tq + 32*i][d];
            #pragma unroll
            for (int j=0;j<8;++j) {
                float4 kv = *(const float4*)&Ks[tk + 8*j][d];
                #pragma unroll
                for (int i=0;i<4;++i)
                    s[i][j] += qv[i].x*kv.x + qv[i].y*kv.y + qv[i].z*kv.z + qv[i].w*kv.w;
            }
        }
        #pragma unroll
        for (int i=0;i<4;++i) {
            int q = tq + 32*i;
            float mv = Msh[q], li = Lish[q] * (1.0f/NH);
            #pragma unroll
            for (int j=0;j<8;++j)
                if (!msk[tk + 8*j])
                    acc[i][j] += __expf(s[i][j] - mv) * li;
        }
    }

    #pragma unroll
    for (int i=0;i<4;++i) {
        int q = qt*128 + tq + 32*i;
        size_t base = ((size_t)b*T_LEN + q) * T_LEN + (size_t)kt*64;
        #pragma unroll
        for (int j=0;j<8;++j)
            avg[base + tk + 8*j] = acc[i][j];
    }
}

// ---------------- K4: output projection ----------------
__global__ __launch_bounds__(256) void k_gemm_out(
    const float* __restrict__ X, const float* __restrict__ Wo,
    const float* __restrict__ bo, float* __restrict__ out)
{
    const int bm = blockIdx.y * 64;
    const int bn = blockIdx.x * 64;
    const int t  = threadIdx.x;
    const int tx = t & 15, ty = t >> 4;

    __shared__ float Xs[16][68];
    __shared__ float Ws[16][68];

    float acc[4][4] = {};
    for (int kt = 0; kt < EMB; kt += 16) {
        {
            int lin = t * 4;
            int row = lin >> 4, col = lin & 15;
            float4 xv = *(const float4*)(X + (size_t)(bm+row)*EMB + kt + col);
            Xs[col+0][row] = xv.x; Xs[col+1][row] = xv.y;
            Xs[col+2][row] = xv.z; Xs[col+3][row] = xv.w;
        }
        {
            int lin = t * 4;
            int row = lin >> 6, col = lin & 63;
            *(float4*)&Ws[row][col] = *(const float4*)(Wo + (size_t)(kt+row)*EMB + bn + col);
        }
        __syncthreads();
        #pragma unroll
        for (int k = 0; k < 16; ++k) {
            float4 a = *(const float4*)&Xs[k][ty*4];
            float4 b = *(const float4*)&Ws[k][tx*4];
            const float av[4]  = {a.x,a.y,a.z,a.w};
            const float bv4[4] = {b.x,b.y,b.z,b.w};
            #pragma unroll
            for (int i=0;i<4;++i)
                #pragma unroll
                for (int j=0;j<4;++j)
                    acc[i][j] = fmaf(av[i], bv4[j], acc[i][j]);
        }
        __syncthreads();
    }
    #pragma unroll
    for (int i=0;i<4;++i) {
        int r = bm + ty*4 + i;
        int c = bn + tx*4;
        float4 w = make_float4(acc[i][0]+bo[c], acc[i][1]+bo[c+1],
                               acc[i][2]+bo[c+2], acc[i][3]+bo[c+3]);
        *(float4*)(out + (size_t)r*EMB + c) = w;
    }
}

extern "C" void kernel_launch(void* const* d_in, const int* in_sizes, int n_in,
                              void* d_out, int out_size, void* d_ws, size_t ws_size,
                              hipStream_t stream) {
    const float* X   = (const float*)d_in[0];
    const int*   kpm = (const int*)  d_in[1];
    const float* Wq  = (const float*)d_in[2];
    const float* bq  = (const float*)d_in[3];
    const float* Wk  = (const float*)d_in[4];
    const float* bk  = (const float*)d_in[5];
    const float* Wv  = (const float*)d_in[6];
    const float* bv  = (const float*)d_in[7];
    const float* Wo  = (const float*)d_in[8];
    const float* bo  = (const float*)d_in[9];

    float* out = (float*)d_out;
    float* ws  = (float*)d_ws;

    const size_t QKV = (size_t)NBH * T_LEN * HD;   // 5,242,880
    float* Q       = ws;
    float* K       = Q + QKV;
    float* V       = K + QKV;
    float* Mrow    = V + QKV;
    float* Linv    = Mrow + (size_t)NBH * T_LEN;
    float* AttnMid = Linv + (size_t)NBH * T_LEN;

    float* attn_out = out;                              // [T_LEN, BSZ, EMB]
    float* avg      = out + (size_t)T_LEN * BSZ * EMB;  // [BSZ, T_LEN, T_LEN]

    k_gemm_qkv<<<dim3(EMB/64, NR/64, 3), 256, 0, stream>>>(X, Wq,bq, Wk,bk, Wv,bv, Q, K, V);
    k_pv      <<<dim3(T_LEN/32, NBH),    256, 0, stream>>>(Q, K, V, kpm, Mrow, Linv, AttnMid);
    k_meanw   <<<dim3(T_LEN/64, T_LEN/128, BSZ), 256, 0, stream>>>(Q, K, kpm, Mrow, Linv, avg);
    k_gemm_out<<<dim3(EMB/64, NR/64),    256, 0, stream>>>(AttnMid, Wo, bo, attn_out);
}

// Round 3
// 1358.977 us; speedup vs baseline: 4.5952x; 1.6195x over previous
//
#include <hip/hip_runtime.h>

#define T_LEN 2048
#define BSZ   2
#define EMB   1280
#define NH    20
#define HD    64
#define NBH   (BSZ*NH)      // 40
#define NR    (T_LEN*BSZ)   // 4096
#define SCALE 0.125f        // HEAD_DIM ** -0.5

#define NEG_INF (-__builtin_inff())

typedef short bf16x8 __attribute__((ext_vector_type(8)));
typedef float f32x4  __attribute__((ext_vector_type(4)));

__device__ inline short f2bf(float f) {
    union { float f; unsigned u; } v; v.f = f;
    unsigned u = v.u + 0x7FFF + ((v.u >> 16) & 1);
    return (short)(u >> 16);
}

// ---------------- K1: QKV projection GEMM ----------------
// C[4096,1280] = X @ W + b (scaled for Q).
// which==0: Qf fp32 + Qb bf16 (both [bh][t][d])
// which==1: Kf fp32 + Kb bf16
// which==2: Vt bf16 transposed [bh][d][t]
__global__ __launch_bounds__(256) void k_gemm_qkv(
    const float* __restrict__ X,
    const float* __restrict__ Wq, const float* __restrict__ bq,
    const float* __restrict__ Wk, const float* __restrict__ bk,
    const float* __restrict__ Wv, const float* __restrict__ bv,
    float* __restrict__ Qf, float* __restrict__ Kf,
    short* __restrict__ Qb, short* __restrict__ Kb, short* __restrict__ Vt)
{
    const int which = blockIdx.z;
    const float* __restrict__ W    = (which==0) ? Wq : (which==1) ? Wk : Wv;
    const float* __restrict__ bias = (which==0) ? bq : (which==1) ? bk : bv;
    const float scale = (which==0) ? SCALE : 1.0f;

    const int bm = blockIdx.y * 64;
    const int bn = blockIdx.x * 64;
    const int t  = threadIdx.x;
    const int tx = t & 15, ty = t >> 4;

    __shared__ float Xs[16][68];   // [k][m]
    __shared__ float Ws[16][68];   // [k][n]

    float acc[4][4] = {};

    for (int kt = 0; kt < EMB; kt += 16) {
        {
            int lin = t * 4;
            int row = lin >> 4, col = lin & 15;
            float4 xv = *(const float4*)(X + (size_t)(bm+row)*EMB + kt + col);
            Xs[col+0][row] = xv.x; Xs[col+1][row] = xv.y;
            Xs[col+2][row] = xv.z; Xs[col+3][row] = xv.w;
        }
        {
            int lin = t * 4;
            int row = lin >> 6, col = lin & 63;
            *(float4*)&Ws[row][col] = *(const float4*)(W + (size_t)(kt+row)*EMB + bn + col);
        }
        __syncthreads();
        #pragma unroll
        for (int k = 0; k < 16; ++k) {
            float4 a = *(const float4*)&Xs[k][ty*4];
            float4 b = *(const float4*)&Ws[k][tx*4];
            const float av[4]  = {a.x,a.y,a.z,a.w};
            const float bv4[4] = {b.x,b.y,b.z,b.w};
            #pragma unroll
            for (int i=0;i<4;++i)
                #pragma unroll
                for (int j=0;j<4;++j)
                    acc[i][j] = fmaf(av[i], bv4[j], acc[i][j]);
        }
        __syncthreads();
    }
    #pragma unroll
    for (int i=0;i<4;++i) {
        int r = bm + ty*4 + i;
        int tt = r >> 1, bb = r & 1;   // r = t*BSZ + b
        #pragma unroll
        for (int j=0;j<4;++j) {
            int c = bn + tx*4 + j;
            int h = c >> 6, d = c & 63;
            float val = (acc[i][j] + bias[c]) * scale;
            size_t hm = (((size_t)(bb*NH+h))*T_LEN + tt)*HD + d;   // head-major [bh][t][d]
            if (which == 0)      { Qf[hm] = val; Qb[hm] = f2bf(val); }
            else if (which == 1) { Kf[hm] = val; Kb[hm] = f2bf(val); }
            else                 { Vt[(((size_t)(bb*NH+h))*HD + d)*T_LEN + tt] = f2bf(val); }
        }
    }
}

// ---------------- K2: MFMA bf16 flash attention (QK^T -> softmax -> PV) ----
// 64 q-rows per block (16 per wave), 32-key tiles. Emits Mrow/Linv for meanw.
__global__ __launch_bounds__(256) void k_pv(
    const short* __restrict__ Qb, const short* __restrict__ Kb, const short* __restrict__ Vt,
    const int* __restrict__ kpm,
    float* __restrict__ Mrow, float* __restrict__ Linv,
    float* __restrict__ AttnMid)   // [4096][1280], r = t*BSZ + b
{
    const int qt = blockIdx.x;          // 32 tiles of 64 q-rows
    const int bh = blockIdx.y;
    const int b  = bh / NH, h = bh % NH;
    const int t    = threadIdx.x;
    const int wave = t >> 6;
    const int lane = t & 63;
    const int l16  = lane & 15;
    const int quad = lane >> 4;
    const int q0   = qt*64 + wave*16;

    __shared__ short Ks[32][72];        // [key][d], stride 144B
    __shared__ short Vts[64][40];       // [d][key], stride 80B
    __shared__ short Ps[4][16][40];     // per-wave P tile [q][key]
    __shared__ int   msk[32];

    // Q A-fragments resident: A[m=l16][k=quad*8+j], two 32-d chunks
    bf16x8 qfrag0, qfrag1;
    {
        const short* qptr = Qb + ((size_t)bh*T_LEN + q0 + l16)*HD + quad*8;
        qfrag0 = *(const bf16x8*)(qptr);
        qfrag1 = *(const bf16x8*)(qptr + 32);
    }

    f32x4 o[4] = {};                    // C-layout: nb -> d=nb*16+l16, row=quad*4+r
    float m[4] = {NEG_INF,NEG_INF,NEG_INF,NEG_INF};
    float l[4] = {};

    for (int kt = 0; kt < T_LEN; kt += 32) {
        __syncthreads();
        {   // stage K tile: 32 rows x 64 d
            int row = t >> 3, col = (t & 7) * 8;
            *(bf16x8*)&Ks[row][col] =
                *(const bf16x8*)(Kb + ((size_t)bh*T_LEN + kt + row)*HD + col);
        }
        {   // stage Vt tile: 64 d-rows x 32 keys
            int row = t >> 2, col = (t & 3) * 8;
            *(bf16x8*)&Vts[row][col] =
                *(const bf16x8*)(Vt + ((size_t)bh*HD + row)*T_LEN + kt + col);
        }
        if (t < 32) msk[t] = kpm[b*T_LEN + kt + t];
        __syncthreads();

        // S = Q @ K^T for 2 key-blocks of 16
        f32x4 s0 = {}, s1 = {};
        {
            bf16x8 kb0 = *(const bf16x8*)&Ks[l16][quad*8];
            bf16x8 kb1 = *(const bf16x8*)&Ks[l16][32+quad*8];
            s0 = __builtin_amdgcn_mfma_f32_16x16x32_bf16(qfrag0, kb0, s0, 0,0,0);
            s0 = __builtin_amdgcn_mfma_f32_16x16x32_bf16(qfrag1, kb1, s0, 0,0,0);
        }
        {
            bf16x8 kb0 = *(const bf16x8*)&Ks[16+l16][quad*8];
            bf16x8 kb1 = *(const bf16x8*)&Ks[16+l16][32+quad*8];
            s1 = __builtin_amdgcn_mfma_f32_16x16x32_bf16(qfrag0, kb0, s1, 0,0,0);
            s1 = __builtin_amdgcn_mfma_f32_16x16x32_bf16(qfrag1, kb1, s1, 0,0,0);
        }

        const bool mk0 = msk[l16] != 0;
        const bool mk1 = msk[16+l16] != 0;

        float p0[4], p1[4], alpha[4];
        #pragma unroll
        for (int r = 0; r < 4; ++r) {
            float sv0 = mk0 ? NEG_INF : s0[r];
            float sv1 = mk1 ? NEG_INF : s1[r];
            float tm = fmaxf(sv0, sv1);
            tm = fmaxf(tm, __shfl_xor(tm, 1, 16));
            tm = fmaxf(tm, __shfl_xor(tm, 2, 16));
            tm = fmaxf(tm, __shfl_xor(tm, 4, 16));
            tm = fmaxf(tm, __shfl_xor(tm, 8, 16));
            float mnew = fmaxf(m[r], tm);
            float a, q0v, q1v;
            if (mnew == NEG_INF) { a = 1.f; q0v = 0.f; q1v = 0.f; }
            else {
                a   = __expf(m[r] - mnew);       // m==-inf -> 0
                q0v = __expf(sv0 - mnew);        // sv==-inf -> 0
                q1v = __expf(sv1 - mnew);
            }
            float psum = q0v + q1v;
            psum += __shfl_xor(psum, 1, 16);
            psum += __shfl_xor(psum, 2, 16);
            psum += __shfl_xor(psum, 4, 16);
            psum += __shfl_xor(psum, 8, 16);
            l[r] = l[r]*a + psum;
            m[r] = mnew;
            alpha[r] = a; p0[r] = q0v; p1[r] = q1v;
        }
        #pragma unroll
        for (int nb = 0; nb < 4; ++nb)
            #pragma unroll
            for (int r = 0; r < 4; ++r)
                o[nb][r] *= alpha[r];

        // P -> LDS (C-layout scatter), then read back as A-fragment
        #pragma unroll
        for (int r = 0; r < 4; ++r) {
            Ps[wave][quad*4+r][l16]    = f2bf(p0[r]);
            Ps[wave][quad*4+r][16+l16] = f2bf(p1[r]);
        }
        bf16x8 pa = *(const bf16x8*)&Ps[wave][l16][quad*8];

        // O += P @ V : 4 d-blocks of 16
        #pragma unroll
        for (int nb = 0; nb < 4; ++nb) {
            bf16x8 vb = *(const bf16x8*)&Vts[nb*16 + l16][quad*8];
            o[nb] = __builtin_amdgcn_mfma_f32_16x16x32_bf16(pa, vb, o[nb], 0,0,0);
        }
    }

    float li[4];
    #pragma unroll
    for (int r = 0; r < 4; ++r) li[r] = 1.0f / l[r];

    if (l16 == 0) {
        #pragma unroll
        for (int r = 0; r < 4; ++r) {
            int q = q0 + quad*4 + r;
            Mrow[(size_t)bh*T_LEN + q] = m[r];
            Linv[(size_t)bh*T_LEN + q] = li[r];
        }
    }
    #pragma unroll
    for (int r = 0; r < 4; ++r) {
        int q = q0 + quad*4 + r;
        size_t base = ((size_t)q*BSZ + b)*EMB + h*HD;
        #pragma unroll
        for (int nb = 0; nb < 4; ++nb)
            AttnMid[base + nb*16 + l16] = o[nb][r] * li[r];
    }
}

// ---------------- K3: avg_weights = mean over heads of P ----------------
__global__ __launch_bounds__(256) void k_meanw(
    const float* __restrict__ Q, const float* __restrict__ K,
    const int* __restrict__ kpm,
    const float* __restrict__ Mrow, const float* __restrict__ Linv,
    float* __restrict__ avg)   // [BSZ][T_LEN][T_LEN]
{
    const int kt = blockIdx.x;   // 32 k-tiles of 64
    const int qt = blockIdx.y;   // 16 q-tiles of 128
    const int b  = blockIdx.z;
    const int t  = threadIdx.x;
    const int tq = t >> 3;       // 0..31
    const int tk = t & 7;        // 0..7

    __shared__ float Qs[128][68];
    __shared__ float Ks[64][68];
    __shared__ float Msh[128], Lish[128];
    __shared__ int   msk[64];

    if (t < 64) msk[t] = kpm[b*T_LEN + kt*64 + t];

    float acc[4][8] = {};

    for (int h = 0; h < NH; ++h) {
        const int bh = b*NH + h;
        __syncthreads();
        {
            const float* src = Q + ((size_t)bh*T_LEN + qt*128)*HD;
            #pragma unroll
            for (int p = 0; p < 8; ++p) {
                int idx = p*256 + t;
                int q = idx >> 4, d = (idx & 15) * 4;
                *(float4*)&Qs[q][d] = *(const float4*)(src + q*HD + d);
            }
        }
        {
            const float* srcK = K + ((size_t)bh*T_LEN + kt*64)*HD;
            #pragma unroll
            for (int p = 0; p < 4; ++p) {
                int idx = p*256 + t;
                int r = idx >> 4, d = (idx & 15) * 4;
                *(float4*)&Ks[r][d] = *(const float4*)(srcK + r*HD + d);
            }
        }
        if (t < 128) {
            Msh[t]  = Mrow[(size_t)bh*T_LEN + qt*128 + t];
            Lish[t] = Linv[(size_t)bh*T_LEN + qt*128 + t];
        }
        __syncthreads();

        float s[4][8] = {};
        #pragma unroll 1
        for (int d = 0; d < HD; d += 4) {
            float4 qv[4];
            #pragma unroll
            for (int i=0;i<4;++i) qv[i] = *(const float4*)&Qs[tq + 32*i][d];
            #pragma unroll
            for (int j=0;j<8;++j) {
                float4 kv = *(const float4*)&Ks[tk + 8*j][d];
                #pragma unroll
                for (int i=0;i<4;++i)
                    s[i][j] += qv[i].x*kv.x + qv[i].y*kv.y + qv[i].z*kv.z + qv[i].w*kv.w;
            }
        }
        #pragma unroll
        for (int i=0;i<4;++i) {
            int q = tq + 32*i;
            float mv = Msh[q], li = Lish[q] * (1.0f/NH);
            #pragma unroll
            for (int j=0;j<8;++j)
                if (!msk[tk + 8*j])
                    acc[i][j] += __expf(s[i][j] - mv) * li;
        }
    }

    #pragma unroll
    for (int i=0;i<4;++i) {
        int q = qt*128 + tq + 32*i;
        size_t base = ((size_t)b*T_LEN + q) * T_LEN + (size_t)kt*64;
        #pragma unroll
        for (int j=0;j<8;++j)
            avg[base + tk + 8*j] = acc[i][j];
    }
}

// ---------------- K4: output projection ----------------
__global__ __launch_bounds__(256) void k_gemm_out(
    const float* __restrict__ X, const float* __restrict__ Wo,
    const float* __restrict__ bo, float* __restrict__ out)
{
    const int bm = blockIdx.y * 64;
    const int bn = blockIdx.x * 64;
    const int t  = threadIdx.x;
    const int tx = t & 15, ty = t >> 4;

    __shared__ float Xs[16][68];
    __shared__ float Ws[16][68];

    float acc[4][4] = {};
    for (int kt = 0; kt < EMB; kt += 16) {
        {
            int lin = t * 4;
            int row = lin >> 4, col = lin & 15;
            float4 xv = *(const float4*)(X + (size_t)(bm+row)*EMB + kt + col);
            Xs[col+0][row] = xv.x; Xs[col+1][row] = xv.y;
            Xs[col+2][row] = xv.z; Xs[col+3][row] = xv.w;
        }
        {
            int lin = t * 4;
            int row = lin >> 6, col = lin & 63;
            *(float4*)&Ws[row][col] = *(const float4*)(Wo + (size_t)(kt+row)*EMB + bn + col);
        }
        __syncthreads();
        #pragma unroll
        for (int k = 0; k < 16; ++k) {
            float4 a = *(const float4*)&Xs[k][ty*4];
            float4 b = *(const float4*)&Ws[k][tx*4];
            const float av[4]  = {a.x,a.y,a.z,a.w};
            const float bv4[4] = {b.x,b.y,b.z,b.w};
            #pragma unroll
            for (int i=0;i<4;++i)
                #pragma unroll
                for (int j=0;j<4;++j)
                    acc[i][j] = fmaf(av[i], bv4[j], acc[i][j]);
        }
        __syncthreads();
    }
    #pragma unroll
    for (int i=0;i<4;++i) {
        int r = bm + ty*4 + i;
        int c = bn + tx*4;
        float4 w = make_float4(acc[i][0]+bo[c], acc[i][1]+bo[c+1],
                               acc[i][2]+bo[c+2], acc[i][3]+bo[c+3]);
        *(float4*)(out + (size_t)r*EMB + c) = w;
    }
}

extern "C" void kernel_launch(void* const* d_in, const int* in_sizes, int n_in,
                              void* d_out, int out_size, void* d_ws, size_t ws_size,
                              hipStream_t stream) {
    const float* X   = (const float*)d_in[0];
    const int*   kpm = (const int*)  d_in[1];
    const float* Wq  = (const float*)d_in[2];
    const float* bq  = (const float*)d_in[3];
    const float* Wk  = (const float*)d_in[4];
    const float* bk  = (const float*)d_in[5];
    const float* Wv  = (const float*)d_in[6];
    const float* bv  = (const float*)d_in[7];
    const float* Wo  = (const float*)d_in[8];
    const float* bo  = (const float*)d_in[9];

    float* out = (float*)d_out;
    float* ws  = (float*)d_ws;

    const size_t QKV = (size_t)NBH * T_LEN * HD;   // 5,242,880
    float* Qf      = ws;
    float* Kf      = Qf + QKV;
    float* Mrow    = Kf + QKV;
    float* Linv    = Mrow + (size_t)NBH * T_LEN;
    float* AttnMid = Linv + (size_t)NBH * T_LEN;
    short* Qb      = (short*)(AttnMid + QKV);
    short* Kb      = Qb + QKV;
    short* Vt      = Kb + QKV;

    float* attn_out = out;                              // [T_LEN, BSZ, EMB]
    float* avg      = out + (size_t)T_LEN * BSZ * EMB;  // [BSZ, T_LEN, T_LEN]

    k_gemm_qkv<<<dim3(EMB/64, NR/64, 3), 256, 0, stream>>>(X, Wq,bq, Wk,bk, Wv,bv,
                                                           Qf, Kf, Qb, Kb, Vt);
    k_pv      <<<dim3(T_LEN/64, NBH),    256, 0, stream>>>(Qb, Kb, Vt, kpm, Mrow, Linv, AttnMid);
    k_meanw   <<<dim3(T_LEN/64, T_LEN/128, BSZ), 256, 0, stream>>>(Qf, Kf, kpm, Mrow, Linv, avg);
    k_gemm_out<<<dim3(EMB/64, NR/64),    256, 0, stream>>>(AttnMid, Wo, bo, attn_out);
}

// Round 4
// 481.844 us; speedup vs baseline: 12.9601x; 2.8204x over previous
//
#include <hip/hip_runtime.h>

#define T_LEN 2048
#define BSZ   2
#define EMB   1280
#define NH    20
#define HD    64
#define NBH   (BSZ*NH)      // 40
#define NR    (T_LEN*BSZ)   // 4096
#define SCALE 0.125f        // HEAD_DIM ** -0.5

#define NEG_INF (-__builtin_inff())

typedef short bf16x8 __attribute__((ext_vector_type(8)));
typedef short bf16x4 __attribute__((ext_vector_type(4)));
typedef float f32x4  __attribute__((ext_vector_type(4)));

__device__ inline short f2bf(float f) {
    union { float f; unsigned u; } v; v.f = f;
    unsigned u = v.u + 0x7FFF + ((v.u >> 16) & 1);
    return (short)(u >> 16);
}

// ---------------- K0a: convert X -> bf16 ----------------
__global__ __launch_bounds__(256) void k_cvt_x(
    const float* __restrict__ X, short* __restrict__ Xb)
{
    size_t i0 = ((size_t)blockIdx.x*256 + threadIdx.x) * 8;
    float4 a = *(const float4*)(X + i0);
    float4 b = *(const float4*)(X + i0 + 4);
    bf16x8 r = { f2bf(a.x), f2bf(a.y), f2bf(a.z), f2bf(a.w),
                 f2bf(b.x), f2bf(b.y), f2bf(b.z), f2bf(b.w) };
    *(bf16x8*)(Xb + i0) = r;
}

// ---------------- K0b: transpose-convert W[k][n] fp32 -> Wt[n][k] bf16 ----
__global__ __launch_bounds__(256) void k_cvt_wt(
    const float* __restrict__ Wq, const float* __restrict__ Wk,
    const float* __restrict__ Wv, const float* __restrict__ Wo,
    short* __restrict__ Wqt, short* __restrict__ Wkt,
    short* __restrict__ Wvt, short* __restrict__ Wot)
{
    const int z = blockIdx.z;
    const float* __restrict__ W = (z==0)?Wq:(z==1)?Wk:(z==2)?Wv:Wo;
    short* __restrict__ Wt      = (z==0)?Wqt:(z==1)?Wkt:(z==2)?Wvt:Wot;

    const int k0 = blockIdx.y * 32;
    const int n0 = blockIdx.x * 32;
    const int t  = threadIdx.x;

    __shared__ float Ls[32][33];
    {
        int row = t >> 3, col = (t & 7) * 4;
        *(float4*)&Ls[row][col] = *(const float4*)(W + (size_t)(k0+row)*EMB + n0 + col);
    }
    __syncthreads();
    {
        int n = t >> 3, k4 = (t & 7) * 4;
        bf16x4 r = { f2bf(Ls[k4+0][n]), f2bf(Ls[k4+1][n]),
                     f2bf(Ls[k4+2][n]), f2bf(Ls[k4+3][n]) };
        *(bf16x4*)(Wt + (size_t)(n0+n)*EMB + k0 + k4) = r;
    }
}

// ---------------- K1: QKV projection, bf16 MFMA 128x128xBK64 ----------------
// C[4096,1280] = Xb @ Wt^T + b (scaled for Q). which: 0->Qb, 1->Kb, 2->Vt.
__global__ __launch_bounds__(256) void k_gemm_qkv(
    const short* __restrict__ Xb,
    const short* __restrict__ Wqt, const short* __restrict__ Wkt, const short* __restrict__ Wvt,
    const float* __restrict__ bq, const float* __restrict__ bk, const float* __restrict__ bv,
    short* __restrict__ Qb, short* __restrict__ Kb, short* __restrict__ Vt)
{
    const int which = blockIdx.z;
    const short* __restrict__ Wt   = (which==0) ? Wqt : (which==1) ? Wkt : Wvt;
    const float* __restrict__ bias = (which==0) ? bq  : (which==1) ? bk  : bv;
    const float scale = (which==0) ? SCALE : 1.0f;

    const int bm = blockIdx.y * 128;
    const int bn = blockIdx.x * 128;
    const int t    = threadIdx.x;
    const int wave = t >> 6, lane = t & 63;
    const int l16  = lane & 15, quad = lane >> 4;
    const int wm   = (wave >> 1) * 64, wn = (wave & 1) * 64;

    __shared__ short As[128][72];
    __shared__ short Bs[128][72];

    f32x4 acc[4][4] = {};

    for (int kt = 0; kt < EMB; kt += 64) {
        __syncthreads();
        const short* Ag = Xb + (size_t)bm*EMB + kt;
        const short* Bg = Wt + (size_t)bn*EMB + kt;
        #pragma unroll
        for (int c = 0; c < 4; ++c) {
            int idx = c*256 + t;
            int row = idx >> 3, col8 = (idx & 7) * 8;
            *(bf16x8*)&As[row][col8] = *(const bf16x8*)(Ag + (size_t)row*EMB + col8);
            *(bf16x8*)&Bs[row][col8] = *(const bf16x8*)(Bg + (size_t)row*EMB + col8);
        }
        __syncthreads();
        #pragma unroll
        for (int ks = 0; ks < 64; ks += 32) {
            bf16x8 af[4], bfr[4];
            #pragma unroll
            for (int mi=0;mi<4;++mi) af[mi]  = *(const bf16x8*)&As[wm + mi*16 + l16][ks + quad*8];
            #pragma unroll
            for (int ni=0;ni<4;++ni) bfr[ni] = *(const bf16x8*)&Bs[wn + ni*16 + l16][ks + quad*8];
            #pragma unroll
            for (int mi=0;mi<4;++mi)
                #pragma unroll
                for (int ni=0;ni<4;++ni)
                    acc[mi][ni] = __builtin_amdgcn_mfma_f32_16x16x32_bf16(af[mi], bfr[ni], acc[mi][ni], 0,0,0);
        }
    }

    #pragma unroll
    for (int ni=0;ni<4;++ni) {
        int c = bn + wn + ni*16 + l16;
        float bval = bias[c];
        int h = c >> 6, d = c & 63;
        #pragma unroll
        for (int mi=0;mi<4;++mi) {
            #pragma unroll
            for (int j=0;j<4;++j) {
                int r = bm + wm + mi*16 + quad*4 + j;
                int tt = r >> 1, bb = r & 1;
                float val = (acc[mi][ni][j] + bval) * scale;
                if (which == 2)
                    Vt[((size_t)(bb*NH+h)*HD + d)*T_LEN + tt] = f2bf(val);
                else {
                    short* dst = (which==0) ? Qb : Kb;
                    dst[((size_t)(bb*NH+h)*T_LEN + tt)*HD + d] = f2bf(val);
                }
            }
        }
    }
}

// ---------------- K2: MFMA bf16 flash attention ----------------
__global__ __launch_bounds__(256) void k_pv(
    const short* __restrict__ Qb, const short* __restrict__ Kb, const short* __restrict__ Vt,
    const int* __restrict__ kpm,
    float* __restrict__ Mrow, float* __restrict__ Linv,
    short* __restrict__ AttnMidb)   // [4096][1280] bf16, r = t*BSZ + b
{
    const int qt = blockIdx.x;
    const int bh = blockIdx.y;
    const int b  = bh / NH, h = bh % NH;
    const int t    = threadIdx.x;
    const int wave = t >> 6;
    const int lane = t & 63;
    const int l16  = lane & 15;
    const int quad = lane >> 4;
    const int q0   = qt*64 + wave*16;

    __shared__ short Ks[32][72];
    __shared__ short Vts[64][40];
    __shared__ short Ps[4][16][40];
    __shared__ int   msk[32];

    bf16x8 qfrag0, qfrag1;
    {
        const short* qptr = Qb + ((size_t)bh*T_LEN + q0 + l16)*HD + quad*8;
        qfrag0 = *(const bf16x8*)(qptr);
        qfrag1 = *(const bf16x8*)(qptr + 32);
    }

    f32x4 o[4] = {};
    float m[4] = {NEG_INF,NEG_INF,NEG_INF,NEG_INF};
    float l[4] = {};

    for (int kt = 0; kt < T_LEN; kt += 32) {
        __syncthreads();
        {
            int row = t >> 3, col = (t & 7) * 8;
            *(bf16x8*)&Ks[row][col] =
                *(const bf16x8*)(Kb + ((size_t)bh*T_LEN + kt + row)*HD + col);
        }
        {
            int row = t >> 2, col = (t & 3) * 8;
            *(bf16x8*)&Vts[row][col] =
                *(const bf16x8*)(Vt + ((size_t)bh*HD + row)*T_LEN + kt + col);
        }
        if (t < 32) msk[t] = kpm[b*T_LEN + kt + t];
        __syncthreads();

        f32x4 s0 = {}, s1 = {};
        {
            bf16x8 kb0 = *(const bf16x8*)&Ks[l16][quad*8];
            bf16x8 kb1 = *(const bf16x8*)&Ks[l16][32+quad*8];
            s0 = __builtin_amdgcn_mfma_f32_16x16x32_bf16(qfrag0, kb0, s0, 0,0,0);
            s0 = __builtin_amdgcn_mfma_f32_16x16x32_bf16(qfrag1, kb1, s0, 0,0,0);
        }
        {
            bf16x8 kb0 = *(const bf16x8*)&Ks[16+l16][quad*8];
            bf16x8 kb1 = *(const bf16x8*)&Ks[16+l16][32+quad*8];
            s1 = __builtin_amdgcn_mfma_f32_16x16x32_bf16(qfrag0, kb0, s1, 0,0,0);
            s1 = __builtin_amdgcn_mfma_f32_16x16x32_bf16(qfrag1, kb1, s1, 0,0,0);
        }

        const bool mk0 = msk[l16] != 0;
        const bool mk1 = msk[16+l16] != 0;

        float p0[4], p1[4], alpha[4];
        #pragma unroll
        for (int r = 0; r < 4; ++r) {
            float sv0 = mk0 ? NEG_INF : s0[r];
            float sv1 = mk1 ? NEG_INF : s1[r];
            float tm = fmaxf(sv0, sv1);
            tm = fmaxf(tm, __shfl_xor(tm, 1, 16));
            tm = fmaxf(tm, __shfl_xor(tm, 2, 16));
            tm = fmaxf(tm, __shfl_xor(tm, 4, 16));
            tm = fmaxf(tm, __shfl_xor(tm, 8, 16));
            float mnew = fmaxf(m[r], tm);
            float a, q0v, q1v;
            if (mnew == NEG_INF) { a = 1.f; q0v = 0.f; q1v = 0.f; }
            else {
                a   = __expf(m[r] - mnew);
                q0v = __expf(sv0 - mnew);
                q1v = __expf(sv1 - mnew);
            }
            float psum = q0v + q1v;
            psum += __shfl_xor(psum, 1, 16);
            psum += __shfl_xor(psum, 2, 16);
            psum += __shfl_xor(psum, 4, 16);
            psum += __shfl_xor(psum, 8, 16);
            l[r] = l[r]*a + psum;
            m[r] = mnew;
            alpha[r] = a; p0[r] = q0v; p1[r] = q1v;
        }
        #pragma unroll
        for (int nb = 0; nb < 4; ++nb)
            #pragma unroll
            for (int r = 0; r < 4; ++r)
                o[nb][r] *= alpha[r];

        #pragma unroll
        for (int r = 0; r < 4; ++r) {
            Ps[wave][quad*4+r][l16]    = f2bf(p0[r]);
            Ps[wave][quad*4+r][16+l16] = f2bf(p1[r]);
        }
        bf16x8 pa = *(const bf16x8*)&Ps[wave][l16][quad*8];

        #pragma unroll
        for (int nb = 0; nb < 4; ++nb) {
            bf16x8 vb = *(const bf16x8*)&Vts[nb*16 + l16][quad*8];
            o[nb] = __builtin_amdgcn_mfma_f32_16x16x32_bf16(pa, vb, o[nb], 0,0,0);
        }
    }

    float li[4];
    #pragma unroll
    for (int r = 0; r < 4; ++r) li[r] = 1.0f / l[r];

    if (l16 == 0) {
        #pragma unroll
        for (int r = 0; r < 4; ++r) {
            int q = q0 + quad*4 + r;
            Mrow[(size_t)bh*T_LEN + q] = m[r];
            Linv[(size_t)bh*T_LEN + q] = li[r];
        }
    }
    #pragma unroll
    for (int r = 0; r < 4; ++r) {
        int q = q0 + quad*4 + r;
        size_t base = ((size_t)q*BSZ + b)*EMB + h*HD;
        #pragma unroll
        for (int nb = 0; nb < 4; ++nb)
            AttnMidb[base + nb*16 + l16] = f2bf(o[nb][r] * li[r]);
    }
}

// ---------------- K3: avg_weights via MFMA, 64q x 64k tile ----------------
__global__ __launch_bounds__(256) void k_meanw(
    const short* __restrict__ Qb, const short* __restrict__ Kb,
    const int* __restrict__ kpm,
    const float* __restrict__ Mrow, const float* __restrict__ Linv,
    float* __restrict__ avg)   // [BSZ][T_LEN][T_LEN]
{
    const int kt = blockIdx.x;   // 32 k-tiles of 64
    const int qt = blockIdx.y;   // 32 q-tiles of 64
    const int b  = blockIdx.z;
    const int t    = threadIdx.x;
    const int wave = t >> 6, lane = t & 63;
    const int l16  = lane & 15, quad = lane >> 4;

    __shared__ short Qs[64][72];
    __shared__ short Ks[64][72];
    __shared__ float Msh[64], Lish[64];
    __shared__ int   msk[64];

    if (t < 64) msk[t] = kpm[b*T_LEN + kt*64 + t];

    f32x4 acc[4] = {};
    const int qrow_in = wave*16 + quad*4;   // + r

    for (int h = 0; h < NH; ++h) {
        const int bh = b*NH + h;
        __syncthreads();
        {
            const short* Qg = Qb + ((size_t)bh*T_LEN + qt*64)*HD;
            const short* Kg = Kb + ((size_t)bh*T_LEN + kt*64)*HD;
            #pragma unroll
            for (int c = 0; c < 2; ++c) {
                int idx = c*256 + t;
                int row = idx >> 3, col8 = (idx & 7) * 8;
                *(bf16x8*)&Qs[row][col8] = *(const bf16x8*)(Qg + (size_t)row*HD + col8);
                *(bf16x8*)&Ks[row][col8] = *(const bf16x8*)(Kg + (size_t)row*HD + col8);
            }
        }
        if (t < 64) {
            Msh[t]  = Mrow[(size_t)bh*T_LEN + qt*64 + t];
            Lish[t] = Linv[(size_t)bh*T_LEN + qt*64 + t];
        }
        __syncthreads();

        bf16x8 aq0 = *(const bf16x8*)&Qs[wave*16 + l16][quad*8];
        bf16x8 aq1 = *(const bf16x8*)&Qs[wave*16 + l16][32 + quad*8];

        float mv[4], lv[4];
        #pragma unroll
        for (int r = 0; r < 4; ++r) {
            mv[r] = Msh[qrow_in + r];
            lv[r] = Lish[qrow_in + r] * (1.0f/NH);
        }

        #pragma unroll
        for (int nb = 0; nb < 4; ++nb) {
            bf16x8 bk0 = *(const bf16x8*)&Ks[nb*16 + l16][quad*8];
            bf16x8 bk1 = *(const bf16x8*)&Ks[nb*16 + l16][32 + quad*8];
            f32x4 s = {};
            s = __builtin_amdgcn_mfma_f32_16x16x32_bf16(aq0, bk0, s, 0,0,0);
            s = __builtin_amdgcn_mfma_f32_16x16x32_bf16(aq1, bk1, s, 0,0,0);
            const bool mk = msk[nb*16 + l16] != 0;
            #pragma unroll
            for (int r = 0; r < 4; ++r)
                acc[nb][r] += mk ? 0.f : __expf(s[r] - mv[r]) * lv[r];
        }
    }

    #pragma unroll
    for (int r = 0; r < 4; ++r) {
        int q = qt*64 + qrow_in + r;
        size_t base = ((size_t)b*T_LEN + q) * T_LEN + (size_t)kt*64;
        #pragma unroll
        for (int nb = 0; nb < 4; ++nb)
            avg[base + nb*16 + l16] = acc[nb][r];
    }
}

// ---------------- K4: output projection, bf16 MFMA 128x128xBK64 ----------------
__global__ __launch_bounds__(256) void k_gemm_out(
    const short* __restrict__ Ab, const short* __restrict__ Wot,
    const float* __restrict__ bo, float* __restrict__ out)
{
    const int bm = blockIdx.y * 128;
    const int bn = blockIdx.x * 128;
    const int t    = threadIdx.x;
    const int wave = t >> 6, lane = t & 63;
    const int l16  = lane & 15, quad = lane >> 4;
    const int wm   = (wave >> 1) * 64, wn = (wave & 1) * 64;

    __shared__ short As[128][72];
    __shared__ short Bs[128][72];

    f32x4 acc[4][4] = {};

    for (int kt = 0; kt < EMB; kt += 64) {
        __syncthreads();
        const short* Ag = Ab  + (size_t)bm*EMB + kt;
        const short* Bg = Wot + (size_t)bn*EMB + kt;
        #pragma unroll
        for (int c = 0; c < 4; ++c) {
            int idx = c*256 + t;
            int row = idx >> 3, col8 = (idx & 7) * 8;
            *(bf16x8*)&As[row][col8] = *(const bf16x8*)(Ag + (size_t)row*EMB + col8);
            *(bf16x8*)&Bs[row][col8] = *(const bf16x8*)(Bg + (size_t)row*EMB + col8);
        }
        __syncthreads();
        #pragma unroll
        for (int ks = 0; ks < 64; ks += 32) {
            bf16x8 af[4], bfr[4];
            #pragma unroll
            for (int mi=0;mi<4;++mi) af[mi]  = *(const bf16x8*)&As[wm + mi*16 + l16][ks + quad*8];
            #pragma unroll
            for (int ni=0;ni<4;++ni) bfr[ni] = *(const bf16x8*)&Bs[wn + ni*16 + l16][ks + quad*8];
            #pragma unroll
            for (int mi=0;mi<4;++mi)
                #pragma unroll
                for (int ni=0;ni<4;++ni)
                    acc[mi][ni] = __builtin_amdgcn_mfma_f32_16x16x32_bf16(af[mi], bfr[ni], acc[mi][ni], 0,0,0);
        }
    }

    #pragma unroll
    for (int ni=0;ni<4;++ni) {
        int c = bn + wn + ni*16 + l16;
        float bval = bo[c];
        #pragma unroll
        for (int mi=0;mi<4;++mi) {
            #pragma unroll
            for (int j=0;j<4;++j) {
                int r = bm + wm + mi*16 + quad*4 + j;
                out[(size_t)r*EMB + c] = acc[mi][ni][j] + bval;
            }
        }
    }
}

extern "C" void kernel_launch(void* const* d_in, const int* in_sizes, int n_in,
                              void* d_out, int out_size, void* d_ws, size_t ws_size,
                              hipStream_t stream) {
    const float* X   = (const float*)d_in[0];
    const int*   kpm = (const int*)  d_in[1];
    const float* Wq  = (const float*)d_in[2];
    const float* bq  = (const float*)d_in[3];
    const float* Wk  = (const float*)d_in[4];
    const float* bk  = (const float*)d_in[5];
    const float* Wv  = (const float*)d_in[6];
    const float* bv  = (const float*)d_in[7];
    const float* Wo  = (const float*)d_in[8];
    const float* bo  = (const float*)d_in[9];

    float* out = (float*)d_out;
    float* ws  = (float*)d_ws;

    const size_t QKV = (size_t)NBH * T_LEN * HD;   // 5,242,880
    float* Mrow = ws;
    float* Linv = Mrow + (size_t)NBH * T_LEN;
    short* Xb   = (short*)(Linv + (size_t)NBH * T_LEN);
    short* Wqt  = Xb  + (size_t)NR * EMB;
    short* Wkt  = Wqt + (size_t)EMB * EMB;
    short* Wvt  = Wkt + (size_t)EMB * EMB;
    short* Wot  = Wvt + (size_t)EMB * EMB;
    short* Qb   = Wot + (size_t)EMB * EMB;
    short* Kb   = Qb  + QKV;
    short* Vt   = Kb  + QKV;
    short* Amid = Vt  + QKV;

    float* attn_out = out;                              // [T_LEN, BSZ, EMB]
    float* avg      = out + (size_t)T_LEN * BSZ * EMB;  // [BSZ, T_LEN, T_LEN]

    k_cvt_x   <<<dim3((NR*EMB)/(256*8)), 256, 0, stream>>>(X, Xb);
    k_cvt_wt  <<<dim3(EMB/32, EMB/32, 4), 256, 0, stream>>>(Wq, Wk, Wv, Wo, Wqt, Wkt, Wvt, Wot);
    k_gemm_qkv<<<dim3(EMB/128, NR/128, 3), 256, 0, stream>>>(Xb, Wqt, Wkt, Wvt, bq, bk, bv, Qb, Kb, Vt);
    k_pv      <<<dim3(T_LEN/64, NBH),    256, 0, stream>>>(Qb, Kb, Vt, kpm, Mrow, Linv, Amid);
    k_meanw   <<<dim3(T_LEN/64, T_LEN/64, BSZ), 256, 0, stream>>>(Qb, Kb, kpm, Mrow, Linv, avg);
    k_gemm_out<<<dim3(EMB/128, NR/128),  256, 0, stream>>>(Amid, Wot, bo, attn_out);
}

// Round 5
// 356.262 us; speedup vs baseline: 17.5284x; 1.3525x over previous
//
#include <hip/hip_runtime.h>

#define T_LEN 2048
#define BSZ   2
#define EMB   1280
#define NH    20
#define HD    64
#define NBH   (BSZ*NH)      // 40
#define NR    (T_LEN*BSZ)   // 4096
// HEAD_DIM^-0.5 * (1/ln2): scores computed in log2 domain -> raw v_exp_f32.
// exp2(s/ln2) == exp(s) exactly; Linv/meanw use the same convention.
#define QSCALE (0.125f * 1.4426950408889634f)

typedef short bf16x8 __attribute__((ext_vector_type(8)));
typedef short bf16x4 __attribute__((ext_vector_type(4)));
typedef float f32x4  __attribute__((ext_vector_type(4)));

__device__ inline short f2bf(float f) {
    union { float f; unsigned u; } v; v.f = f;
    unsigned u = v.u + 0x7FFF + ((v.u >> 16) & 1);
    return (short)(u >> 16);
}

// ---------------- K0a: convert X -> bf16 ----------------
__global__ __launch_bounds__(256) void k_cvt_x(
    const float* __restrict__ X, short* __restrict__ Xb)
{
    size_t i0 = ((size_t)blockIdx.x*256 + threadIdx.x) * 8;
    float4 a = *(const float4*)(X + i0);
    float4 b = *(const float4*)(X + i0 + 4);
    bf16x8 r = { f2bf(a.x), f2bf(a.y), f2bf(a.z), f2bf(a.w),
                 f2bf(b.x), f2bf(b.y), f2bf(b.z), f2bf(b.w) };
    *(bf16x8*)(Xb + i0) = r;
}

// ---------------- K0b: transpose-convert W[k][n] fp32 -> Wt[n][k] bf16 ----
__global__ __launch_bounds__(256) void k_cvt_wt(
    const float* __restrict__ Wq, const float* __restrict__ Wk,
    const float* __restrict__ Wv, const float* __restrict__ Wo,
    short* __restrict__ Wqt, short* __restrict__ Wkt,
    short* __restrict__ Wvt, short* __restrict__ Wot)
{
    const int z = blockIdx.z;
    const float* __restrict__ W = (z==0)?Wq:(z==1)?Wk:(z==2)?Wv:Wo;
    short* __restrict__ Wt      = (z==0)?Wqt:(z==1)?Wkt:(z==2)?Wvt:Wot;

    const int k0 = blockIdx.y * 32;
    const int n0 = blockIdx.x * 32;
    const int t  = threadIdx.x;

    __shared__ float Ls[32][33];
    {
        int row = t >> 3, col = (t & 7) * 4;
        *(float4*)&Ls[row][col] = *(const float4*)(W + (size_t)(k0+row)*EMB + n0 + col);
    }
    __syncthreads();
    {
        int n = t >> 3, k4 = (t & 7) * 4;
        bf16x4 r = { f2bf(Ls[k4+0][n]), f2bf(Ls[k4+1][n]),
                     f2bf(Ls[k4+2][n]), f2bf(Ls[k4+3][n]) };
        *(bf16x4*)(Wt + (size_t)(n0+n)*EMB + k0 + k4) = r;
    }
}

// ---------------- K1: QKV projection, bf16 MFMA 128x128xBK64 ----------------
__global__ __launch_bounds__(256) void k_gemm_qkv(
    const short* __restrict__ Xb,
    const short* __restrict__ Wqt, const short* __restrict__ Wkt, const short* __restrict__ Wvt,
    const float* __restrict__ bq, const float* __restrict__ bk, const float* __restrict__ bv,
    short* __restrict__ Qb, short* __restrict__ Kb, short* __restrict__ Vt)
{
    const int which = blockIdx.z;
    const short* __restrict__ Wt   = (which==0) ? Wqt : (which==1) ? Wkt : Wvt;
    const float* __restrict__ bias = (which==0) ? bq  : (which==1) ? bk  : bv;
    const float scale = (which==0) ? QSCALE : 1.0f;

    const int bm = blockIdx.y * 128;
    const int bn = blockIdx.x * 128;
    const int t    = threadIdx.x;
    const int wave = t >> 6, lane = t & 63;
    const int l16  = lane & 15, quad = lane >> 4;
    const int wm   = (wave >> 1) * 64, wn = (wave & 1) * 64;

    __shared__ short As[128][72];
    __shared__ short Bs[128][72];

    f32x4 acc[4][4] = {};

    for (int kt = 0; kt < EMB; kt += 64) {
        __syncthreads();
        const short* Ag = Xb + (size_t)bm*EMB + kt;
        const short* Bg = Wt + (size_t)bn*EMB + kt;
        #pragma unroll
        for (int c = 0; c < 4; ++c) {
            int idx = c*256 + t;
            int row = idx >> 3, col8 = (idx & 7) * 8;
            *(bf16x8*)&As[row][col8] = *(const bf16x8*)(Ag + (size_t)row*EMB + col8);
            *(bf16x8*)&Bs[row][col8] = *(const bf16x8*)(Bg + (size_t)row*EMB + col8);
        }
        __syncthreads();
        #pragma unroll
        for (int ks = 0; ks < 64; ks += 32) {
            bf16x8 af[4], bfr[4];
            #pragma unroll
            for (int mi=0;mi<4;++mi) af[mi]  = *(const bf16x8*)&As[wm + mi*16 + l16][ks + quad*8];
            #pragma unroll
            for (int ni=0;ni<4;++ni) bfr[ni] = *(const bf16x8*)&Bs[wn + ni*16 + l16][ks + quad*8];
            #pragma unroll
            for (int mi=0;mi<4;++mi)
                #pragma unroll
                for (int ni=0;ni<4;++ni)
                    acc[mi][ni] = __builtin_amdgcn_mfma_f32_16x16x32_bf16(af[mi], bfr[ni], acc[mi][ni], 0,0,0);
        }
    }

    #pragma unroll
    for (int ni=0;ni<4;++ni) {
        int c = bn + wn + ni*16 + l16;
        float bval = bias[c];
        int h = c >> 6, d = c & 63;
        #pragma unroll
        for (int mi=0;mi<4;++mi) {
            #pragma unroll
            for (int j=0;j<4;++j) {
                int r = bm + wm + mi*16 + quad*4 + j;
                int tt = r >> 1, bb = r & 1;
                float val = (acc[mi][ni][j] + bval) * scale;
                if (which == 2)
                    Vt[((size_t)(bb*NH+h)*HD + d)*T_LEN + tt] = f2bf(val);
                else {
                    short* dst = (which==0) ? Qb : Kb;
                    dst[((size_t)(bb*NH+h)*T_LEN + tt)*HD + d] = f2bf(val);
                }
            }
        }
    }
}

// ---------------- K2: MFMA flash attention, no-max exp2 softmax -----------
// Block: 4 waves x 32 q = 128 q-rows; K-tiles of 64.
// S computed TRANSPOSED (A=K, B=Q) so each lane holds 4 consecutive keys ->
// P stored to LDS with b64 writes; PV reads P back as A-fragments.
__global__ __launch_bounds__(256) void k_pv(
    const short* __restrict__ Qb, const short* __restrict__ Kb, const short* __restrict__ Vt,
    const int* __restrict__ kpm,
    float* __restrict__ Linv,
    short* __restrict__ AttnMidb)   // [4096][1280] bf16, r = t*BSZ + b
{
    const int qt = blockIdx.x;          // 16 tiles of 128 q
    const int bh = blockIdx.y;
    const int b  = bh / NH, h = bh % NH;
    const int t    = threadIdx.x;
    const int w    = t >> 6;
    const int lane = t & 63;
    const int l16  = lane & 15;
    const int quad = lane >> 4;
    const int q0   = qt*128 + w*32;     // wave's first q-row

    __shared__ short Ks[64][72];        // [key][d]
    __shared__ short Vts[64][72];       // [d][key]
    __shared__ short Ps[4][32][40];     // per-wave [q][key-in-chunk(32)]
    __shared__ float Mf[64];            // mask floats for current tile
    __shared__ float Lsh[128];

    // Q fragments resident: used as MFMA *B* operand (n=q, k=d)
    bf16x8 qf[2][2];
    #pragma unroll
    for (int mi=0;mi<2;++mi)
        #pragma unroll
        for (int ch=0;ch<2;++ch)
            qf[mi][ch] = *(const bf16x8*)(Qb + ((size_t)bh*T_LEN + q0 + mi*16 + l16)*HD + ch*32 + quad*8);

    f32x4 o[2][4] = {};                 // [q-block][d-block], C-layout
    float l[2] = {0.f, 0.f};            // per-quad partial row sums

    for (int kt = 0; kt < T_LEN; kt += 64) {
        __syncthreads();
        #pragma unroll
        for (int c2 = 0; c2 < 2; ++c2) {
            int idx = c2*256 + t;
            int row = idx >> 3, col8 = (idx & 7)*8;
            *(bf16x8*)&Ks[row][col8]  = *(const bf16x8*)(Kb + ((size_t)bh*T_LEN + kt + row)*HD + col8);
            *(bf16x8*)&Vts[row][col8] = *(const bf16x8*)(Vt + ((size_t)bh*HD + row)*T_LEN + kt + col8);
        }
        if (t < 64) Mf[t] = kpm[b*T_LEN + kt + t] ? 0.f : 1.f;
        __syncthreads();

        // S^T[key][q]: lane holds q = mi*16+l16 (col), key = mb*16+quad*4+r (row)
        f32x4 s[4][2] = {};
        #pragma unroll
        for (int ch = 0; ch < 2; ++ch) {
            bf16x8 ka[4];
            #pragma unroll
            for (int mb=0;mb<4;++mb) ka[mb] = *(const bf16x8*)&Ks[mb*16 + l16][ch*32 + quad*8];
            #pragma unroll
            for (int mb=0;mb<4;++mb)
                #pragma unroll
                for (int mi=0;mi<2;++mi)
                    s[mb][mi] = __builtin_amdgcn_mfma_f32_16x16x32_bf16(ka[mb], qf[mi][ch], s[mb][mi], 0,0,0);
        }

        // two key-chunks of 32: p = exp2(s)*mask, accumulate l, b64-pack P, PV
        #pragma unroll
        for (int c = 0; c < 2; ++c) {
            #pragma unroll
            for (int mb2 = 0; mb2 < 2; ++mb2) {
                const int mb = c*2 + mb2;
                float4 mf = *(const float4*)&Mf[mb*16 + quad*4];
                #pragma unroll
                for (int mi = 0; mi < 2; ++mi) {
                    float p0 = __builtin_amdgcn_exp2f(s[mb][mi][0]) * mf.x;
                    float p1 = __builtin_amdgcn_exp2f(s[mb][mi][1]) * mf.y;
                    float p2 = __builtin_amdgcn_exp2f(s[mb][mi][2]) * mf.z;
                    float p3 = __builtin_amdgcn_exp2f(s[mb][mi][3]) * mf.w;
                    l[mi] += (p0 + p1) + (p2 + p3);
                    unsigned d0 = ((unsigned)(unsigned short)f2bf(p1) << 16) | (unsigned short)f2bf(p0);
                    unsigned d1 = ((unsigned)(unsigned short)f2bf(p3) << 16) | (unsigned short)f2bf(p2);
                    uint2 dd; dd.x = d0; dd.y = d1;
                    *(uint2*)&Ps[w][mi*16 + l16][mb2*16 + quad*4] = dd;
                }
            }
            #pragma unroll
            for (int mi=0;mi<2;++mi) {
                bf16x8 pa = *(const bf16x8*)&Ps[w][mi*16 + l16][quad*8];
                #pragma unroll
                for (int nb=0;nb<4;++nb) {
                    bf16x8 vb = *(const bf16x8*)&Vts[nb*16 + l16][c*32 + quad*8];
                    o[mi][nb] = __builtin_amdgcn_mfma_f32_16x16x32_bf16(pa, vb, o[mi][nb], 0,0,0);
                }
            }
        }
    }

    // finalize l: reduce across quads (only cross-lane op in the kernel)
    #pragma unroll
    for (int mi=0;mi<2;++mi) {
        l[mi] += __shfl_xor(l[mi], 16);
        l[mi] += __shfl_xor(l[mi], 32);
        float linv = 1.0f / l[mi];
        if (quad == 0) {
            Linv[(size_t)bh*T_LEN + q0 + mi*16 + l16] = linv;
            Lsh[w*32 + mi*16 + l16] = linv;
        }
    }
    // per-wave region of Lsh; same-wave ds ordering suffices (no barrier)
    #pragma unroll
    for (int mi=0;mi<2;++mi) {
        float4 li = *(const float4*)&Lsh[w*32 + mi*16 + quad*4];
        float lr[4] = {li.x, li.y, li.z, li.w};
        #pragma unroll
        for (int r=0;r<4;++r) {
            int q = q0 + mi*16 + quad*4 + r;
            size_t base = ((size_t)q*BSZ + b)*EMB + h*HD;
            #pragma unroll
            for (int nb=0;nb<4;++nb)
                AttnMidb[base + nb*16 + l16] = f2bf(o[mi][nb][r] * lr[r]);
        }
    }
}

// ---------------- K3: avg_weights via MFMA, 64q x 64k tile ----------------
__global__ __launch_bounds__(256) void k_meanw(
    const short* __restrict__ Qb, const short* __restrict__ Kb,
    const int* __restrict__ kpm,
    const float* __restrict__ Linv,
    float* __restrict__ avg)   // [BSZ][T_LEN][T_LEN]
{
    const int kt = blockIdx.x;   // 32 k-tiles of 64
    const int qt = blockIdx.y;   // 32 q-tiles of 64
    const int b  = blockIdx.z;
    const int t    = threadIdx.x;
    const int wave = t >> 6, lane = t & 63;
    const int l16  = lane & 15, quad = lane >> 4;

    __shared__ short Qs[64][72];
    __shared__ short Ks[64][72];
    __shared__ float Lish[64];
    __shared__ int   msk[64];

    if (t < 64) msk[t] = kpm[b*T_LEN + kt*64 + t];

    f32x4 acc[4] = {};
    const int qrow_in = wave*16 + quad*4;   // + r

    for (int h = 0; h < NH; ++h) {
        const int bh = b*NH + h;
        __syncthreads();
        {
            const short* Qg = Qb + ((size_t)bh*T_LEN + qt*64)*HD;
            const short* Kg = Kb + ((size_t)bh*T_LEN + kt*64)*HD;
            #pragma unroll
            for (int c = 0; c < 2; ++c) {
                int idx = c*256 + t;
                int row = idx >> 3, col8 = (idx & 7) * 8;
                *(bf16x8*)&Qs[row][col8] = *(const bf16x8*)(Qg + (size_t)row*HD + col8);
                *(bf16x8*)&Ks[row][col8] = *(const bf16x8*)(Kg + (size_t)row*HD + col8);
            }
        }
        if (t < 64) Lish[t] = Linv[(size_t)bh*T_LEN + qt*64 + t];
        __syncthreads();

        bf16x8 aq0 = *(const bf16x8*)&Qs[wave*16 + l16][quad*8];
        bf16x8 aq1 = *(const bf16x8*)&Qs[wave*16 + l16][32 + quad*8];

        float lv[4];
        #pragma unroll
        for (int r = 0; r < 4; ++r)
            lv[r] = Lish[qrow_in + r] * (1.0f/NH);

        #pragma unroll
        for (int nb = 0; nb < 4; ++nb) {
            bf16x8 bk0 = *(const bf16x8*)&Ks[nb*16 + l16][quad*8];
            bf16x8 bk1 = *(const bf16x8*)&Ks[nb*16 + l16][32 + quad*8];
            f32x4 s = {};
            s = __builtin_amdgcn_mfma_f32_16x16x32_bf16(aq0, bk0, s, 0,0,0);
            s = __builtin_amdgcn_mfma_f32_16x16x32_bf16(aq1, bk1, s, 0,0,0);
            const bool mk = msk[nb*16 + l16] != 0;
            #pragma unroll
            for (int r = 0; r < 4; ++r)
                acc[nb][r] += mk ? 0.f : __builtin_amdgcn_exp2f(s[r]) * lv[r];
        }
    }

    #pragma unroll
    for (int r = 0; r < 4; ++r) {
        int q = qt*64 + qrow_in + r;
        size_t base = ((size_t)b*T_LEN + q) * T_LEN + (size_t)kt*64;
        #pragma unroll
        for (int nb = 0; nb < 4; ++nb)
            avg[base + nb*16 + l16] = acc[nb][r];
    }
}

// ---------------- K4: output projection, bf16 MFMA 128x128xBK64 ------------
__global__ __launch_bounds__(256) void k_gemm_out(
    const short* __restrict__ Ab, const short* __restrict__ Wot,
    const float* __restrict__ bo, float* __restrict__ out)
{
    const int bm = blockIdx.y * 128;
    const int bn = blockIdx.x * 128;
    const int t    = threadIdx.x;
    const int wave = t >> 6, lane = t & 63;
    const int l16  = lane & 15, quad = lane >> 4;
    const int wm   = (wave >> 1) * 64, wn = (wave & 1) * 64;

    __shared__ short As[128][72];
    __shared__ short Bs[128][72];

    f32x4 acc[4][4] = {};

    for (int kt = 0; kt < EMB; kt += 64) {
        __syncthreads();
        const short* Ag = Ab  + (size_t)bm*EMB + kt;
        const short* Bg = Wot + (size_t)bn*EMB + kt;
        #pragma unroll
        for (int c = 0; c < 4; ++c) {
            int idx = c*256 + t;
            int row = idx >> 3, col8 = (idx & 7) * 8;
            *(bf16x8*)&As[row][col8] = *(const bf16x8*)(Ag + (size_t)row*EMB + col8);
            *(bf16x8*)&Bs[row][col8] = *(const bf16x8*)(Bg + (size_t)row*EMB + col8);
        }
        __syncthreads();
        #pragma unroll
        for (int ks = 0; ks < 64; ks += 32) {
            bf16x8 af[4], bfr[4];
            #pragma unroll
            for (int mi=0;mi<4;++mi) af[mi]  = *(const bf16x8*)&As[wm + mi*16 + l16][ks + quad*8];
            #pragma unroll
            for (int ni=0;ni<4;++ni) bfr[ni] = *(const bf16x8*)&Bs[wn + ni*16 + l16][ks + quad*8];
            #pragma unroll
            for (int mi=0;mi<4;++mi)
                #pragma unroll
                for (int ni=0;ni<4;++ni)
                    acc[mi][ni] = __builtin_amdgcn_mfma_f32_16x16x32_bf16(af[mi], bfr[ni], acc[mi][ni], 0,0,0);
        }
    }

    #pragma unroll
    for (int ni=0;ni<4;++ni) {
        int c = bn + wn + ni*16 + l16;
        float bval = bo[c];
        #pragma unroll
        for (int mi=0;mi<4;++mi) {
            #pragma unroll
            for (int j=0;j<4;++j) {
                int r = bm + wm + mi*16 + quad*4 + j;
                out[(size_t)r*EMB + c] = acc[mi][ni][j] + bval;
            }
        }
    }
}

extern "C" void kernel_launch(void* const* d_in, const int* in_sizes, int n_in,
                              void* d_out, int out_size, void* d_ws, size_t ws_size,
                              hipStream_t stream) {
    const float* X   = (const float*)d_in[0];
    const int*   kpm = (const int*)  d_in[1];
    const float* Wq  = (const float*)d_in[2];
    const float* bq  = (const float*)d_in[3];
    const float* Wk  = (const float*)d_in[4];
    const float* bk  = (const float*)d_in[5];
    const float* Wv  = (const float*)d_in[6];
    const float* bv  = (const float*)d_in[7];
    const float* Wo  = (const float*)d_in[8];
    const float* bo  = (const float*)d_in[9];

    float* out = (float*)d_out;
    float* ws  = (float*)d_ws;

    const size_t QKV = (size_t)NBH * T_LEN * HD;   // 5,242,880
    float* Linv = ws;
    short* Xb   = (short*)(Linv + (size_t)NBH * T_LEN);
    short* Wqt  = Xb  + (size_t)NR * EMB;
    short* Wkt  = Wqt + (size_t)EMB * EMB;
    short* Wvt  = Wkt + (size_t)EMB * EMB;
    short* Wot  = Wvt + (size_t)EMB * EMB;
    short* Qb   = Wot + (size_t)EMB * EMB;
    short* Kb   = Qb  + QKV;
    short* Vt   = Kb  + QKV;
    short* Amid = Vt  + QKV;

    float* attn_out = out;                              // [T_LEN, BSZ, EMB]
    float* avg      = out + (size_t)T_LEN * BSZ * EMB;  // [BSZ, T_LEN, T_LEN]

    k_cvt_x   <<<dim3((NR*EMB)/(256*8)), 256, 0, stream>>>(X, Xb);
    k_cvt_wt  <<<dim3(EMB/32, EMB/32, 4), 256, 0, stream>>>(Wq, Wk, Wv, Wo, Wqt, Wkt, Wvt, Wot);
    k_gemm_qkv<<<dim3(EMB/128, NR/128, 3), 256, 0, stream>>>(Xb, Wqt, Wkt, Wvt, bq, bk, bv, Qb, Kb, Vt);
    k_pv      <<<dim3(T_LEN/128, NBH),   256, 0, stream>>>(Qb, Kb, Vt, kpm, Linv, Amid);
    k_meanw   <<<dim3(T_LEN/64, T_LEN/64, BSZ), 256, 0, stream>>>(Qb, Kb, kpm, Linv, avg);
    k_gemm_out<<<dim3(EMB/128, NR/128),  256, 0, stream>>>(Amid, Wot, bo, attn_out);
}